// Round 2
// baseline (221.824 us; speedup 1.0000x reference)
//
#include <hip/hip_runtime.h>
#include <hip/hip_bf16.h>

#define B_DIM 8
#define C_DIM 256
#define S_DIM 2304

typedef __attribute__((ext_vector_type(8))) short short8;
typedef __attribute__((ext_vector_type(4))) float floatx4;

// Async global->LDS, 16B per lane. LDS dest is wave-uniform base + lane*16.
__device__ __forceinline__ void gload_lds16(const __hip_bfloat16* g, __hip_bfloat16* l) {
    __builtin_amdgcn_global_load_lds(
        (__attribute__((address_space(1))) void*)(void*)(g),
        (__attribute__((address_space(3))) void*)(l), 16, 0, 0);
}

// ---------------------------------------------------------------------------
// Kernel 1: per-(b,s) L2-normalize over C and transpose [B,C,S] f32 ->
// [B,S,C] bf16.  Block = 256 threads handles 64 s-columns x 256 channels.
// (unchanged from round 1 — est. well under 20 us; revisit only if round-2
//  delta shows gemm wasn't the bulk of dur_us)
// ---------------------------------------------------------------------------
__global__ __launch_bounds__(256) void norm_transpose_kernel(
    const float* __restrict__ src, const float* __restrict__ dst,
    __hip_bfloat16* __restrict__ srcT, __hip_bfloat16* __restrict__ dstT) {
    const int s0 = blockIdx.x * 64;
    const int b  = blockIdx.y;
    const float* in = (blockIdx.z == 0 ? src : dst) + (size_t)b * C_DIM * S_DIM;
    __hip_bfloat16* out = (blockIdx.z == 0 ? srcT : dstT) + (size_t)b * S_DIM * C_DIM;

    __shared__ __align__(16) __hip_bfloat16 tile[64][C_DIM + 8];
    __shared__ float red[4][64];
    __shared__ float invn[64];

    const int t  = threadIdx.x;
    const int l  = t & 63;
    const int wv = t >> 6;

    float ss = 0.f;
#pragma unroll 8
    for (int c = wv; c < C_DIM; c += 4) {
        float v = in[(size_t)c * S_DIM + s0 + l];
        ss += v * v;
        tile[l][c] = __float2bfloat16(v);
    }
    red[wv][l] = ss;
    __syncthreads();
    if (t < 64) invn[t] = rsqrtf(red[0][t] + red[1][t] + red[2][t] + red[3][t]);
    __syncthreads();

#pragma unroll
    for (int it = 0; it < 8; ++it) {
        int idx  = it * 256 + t;
        int srow = idx >> 5;
        int c0   = (idx & 31) << 3;
        float inv = invn[srow];
        union { short8 v; __hip_bfloat16 h[8]; } u, o;
        u.v = *(const short8*)&tile[srow][c0];
#pragma unroll
        for (int j = 0; j < 8; ++j)
            o.h[j] = __float2bfloat16(__bfloat162float(u.h[j]) * inv);
        *(short8*)&out[(size_t)(s0 + srow) * C_DIM + c0] = o.v;
    }
}

// ---------------------------------------------------------------------------
// Kernel 2: per-batch GEMM  out[b][m][n] = relu( sum_k At[b][m][k]*Bt[b][n][k] )
// Round-2 changes vs round-1:
//  * double-buffered LDS staging, ONE barrier per K-iter, prefetch issued
//    after the barrier so it overlaps ds_read+MFMA of the current tile
//  * epilogue: acc -> padded LDS f32 tile (aliased over staging bufs,
//    2-way bank writes = free) -> coalesced float4 global stores
//    (16 b128 stores/thread instead of 64 scalar dword stores)
// ---------------------------------------------------------------------------
__global__ __launch_bounds__(256) void gemm_relu_kernel(
    const __hip_bfloat16* __restrict__ At, const __hip_bfloat16* __restrict__ Bt,
    float* __restrict__ out) {
    const int b  = blockIdx.z;
    const int m0 = blockIdx.y * 128;
    const int n0 = blockIdx.x * 128;
    const __hip_bfloat16* A  = At + (size_t)b * S_DIM * C_DIM;
    const __hip_bfloat16* Bp = Bt + (size_t)b * S_DIM * C_DIM;

    // LDS union:
    //   staging: As[p] at bytes [p*8192, p*8192+8192), p=0,1   (128x32 bf16 each)
    //            Bs[p] at bytes [16384+p*8192, ...)
    //   epilogue: Cs = f32 [64][132] = 33792 B (aliased, used after K-loop)
    __shared__ __align__(16) unsigned char smem[33792];
    __hip_bfloat16* stg = (__hip_bfloat16*)smem;   // element (bf16) indexing
    float* Cs = (float*)smem;

    const int t    = threadIdx.x;
    const int lane = t & 63;
    const int wv   = t >> 6;

    const int fm = lane & 15;          // m (or n) within 16x16 fragment
    const int kq = (lane >> 4) << 3;   // k offset 0/8/16/24
    const int wr = (wv >> 1) << 6;     // wave row origin (0 or 64)
    const int wc = (wv & 1) << 6;      // wave col origin (0 or 64)
    const int rq = (lane >> 4) << 2;   // C/D row quad

    // Staging decomposition: one 128x32 tile = 8 chunks of 1024 B (64 lanes x 16B).
    // Wave wv owns chunks {2wv, 2wv+1}.  Element idx e = ch*512 + lane*8.
    const int ch0   = wv * 2;
    const int e0    = ch0 * 512 + lane * 8;
    const int row0  = e0 >> 5;          // row for chunk ch0
    const int kc0   = e0 & 31;
    const int e1    = (ch0 + 1) * 512 + lane * 8;
    const int row1  = e1 >> 5;
    const int kc1   = e1 & 31;

    floatx4 acc[4][4] = {};

    // prologue: stage tile k0=0 into buffer 0
    {
        gload_lds16(A  + (size_t)(m0 + row0) * C_DIM + kc0, stg + 0 * 4096 + ch0 * 512);
        gload_lds16(A  + (size_t)(m0 + row1) * C_DIM + kc1, stg + 0 * 4096 + (ch0 + 1) * 512);
        gload_lds16(Bp + (size_t)(n0 + row0) * C_DIM + kc0, stg + 8192 + 0 * 4096 + ch0 * 512);
        gload_lds16(Bp + (size_t)(n0 + row1) * C_DIM + kc1, stg + 8192 + 0 * 4096 + (ch0 + 1) * 512);
    }

#pragma unroll
    for (int ki = 0; ki < 8; ++ki) {
        __syncthreads();   // buf[ki&1] staged; prior-iter reads of buf[(ki+1)&1] done

        if (ki < 7) {      // prefetch next tile into the other buffer (overlaps compute)
            int kn = (ki + 1) * 32;
            int pb = (ki + 1) & 1;
            gload_lds16(A  + (size_t)(m0 + row0) * C_DIM + (kn + kc0), stg + pb * 4096 + ch0 * 512);
            gload_lds16(A  + (size_t)(m0 + row1) * C_DIM + (kn + kc1), stg + pb * 4096 + (ch0 + 1) * 512);
            gload_lds16(Bp + (size_t)(n0 + row0) * C_DIM + (kn + kc0), stg + 8192 + pb * 4096 + ch0 * 512);
            gload_lds16(Bp + (size_t)(n0 + row1) * C_DIM + (kn + kc1), stg + 8192 + pb * 4096 + (ch0 + 1) * 512);
        }

        const __hip_bfloat16* AsP = stg + (ki & 1) * 4096;
        const __hip_bfloat16* BsP = stg + 8192 + (ki & 1) * 4096;
        short8 af[4], bf[4];
#pragma unroll
        for (int i = 0; i < 4; ++i) {
            af[i] = *(const short8*)&AsP[(wr + i * 16 + fm) * 32 + kq];
            bf[i] = *(const short8*)&BsP[(wc + i * 16 + fm) * 32 + kq];
        }
#pragma unroll
        for (int i = 0; i < 4; ++i)
#pragma unroll
            for (int j = 0; j < 4; ++j)
                acc[i][j] = __builtin_amdgcn_mfma_f32_16x16x32_bf16(af[i], bf[j], acc[i][j], 0, 0, 0);
    }

    // Epilogue: two rounds through Cs (64 local rows x 132-padded f32), ReLU fused.
    // acc[i][j][r] maps to local row = wr + i*16 + rq + r, local col = wc + j*16 + fm.
    float* Cp = out + (size_t)b * S_DIM * S_DIM;
#pragma unroll
    for (int p = 0; p < 2; ++p) {
        __syncthreads();   // p=0: frag ds_reads done; p=1: round-0 Cs reads done
#pragma unroll
        for (int i2 = 0; i2 < 2; ++i2) {
            int i = 2 * p + i2;
            int slot = (wr >> 1) + i2 * 16 + rq;   // + r below; [0,64)
#pragma unroll
            for (int j = 0; j < 4; ++j) {
                int col = wc + j * 16 + fm;
#pragma unroll
                for (int r = 0; r < 4; ++r)
                    Cs[(slot + r) * 132 + col] = fmaxf(acc[i][j][r], 0.f);
            }
        }
        __syncthreads();
        // 8192 floats -> 8 float4 per thread, coalesced (32 lanes cover one 128-col row)
#pragma unroll
        for (int it = 0; it < 8; ++it) {
            int idx  = it * 256 + t;        // 0..2047 float4 slots
            int srow = idx >> 5;            // 0..63
            int c4   = (idx & 31) << 2;     // local col (multiple of 4)
            float4 v = *(const float4*)&Cs[srow * 132 + c4];
            int lrow = 32 * p + (srow & 31) + ((srow >> 5) << 6);
            *(float4*)&Cp[(size_t)(m0 + lrow) * S_DIM + n0 + c4] = v;
        }
    }
}

extern "C" void kernel_launch(void* const* d_in, const int* in_sizes, int n_in,
                              void* d_out, int out_size, void* d_ws, size_t ws_size,
                              hipStream_t stream) {
    const float* src = (const float*)d_in[0];
    const float* dst = (const float*)d_in[1];
    float* out = (float*)d_out;

    __hip_bfloat16* srcT = (__hip_bfloat16*)d_ws;
    __hip_bfloat16* dstT = srcT + (size_t)B_DIM * S_DIM * C_DIM;

    dim3 g1(S_DIM / 64, B_DIM, 2);
    norm_transpose_kernel<<<g1, 256, 0, stream>>>(src, dst, srcT, dstT);

    dim3 g2(S_DIM / 128, S_DIM / 128, B_DIM);
    gemm_relu_kernel<<<g2, 256, 0, stream>>>(srcT, dstT, out);
}

// Round 3
// 217.338 us; speedup vs baseline: 1.0206x; 1.0206x over previous
//
#include <hip/hip_runtime.h>
#include <hip/hip_bf16.h>

#define B_DIM 8
#define C_DIM 256
#define S_DIM 2304

typedef __attribute__((ext_vector_type(8))) short short8;
typedef __attribute__((ext_vector_type(4))) float floatx4;

// Async global->LDS, 16B per lane. LDS dest is wave-uniform base + lane*16.
__device__ __forceinline__ void gload_lds16(const __hip_bfloat16* g, __hip_bfloat16* l) {
    __builtin_amdgcn_global_load_lds(
        (__attribute__((address_space(1))) void*)(void*)(g),
        (__attribute__((address_space(3))) void*)(l), 16, 0, 0);
}

// ---------------------------------------------------------------------------
// Kernel 1: per-(b,s) L2-normalize over C and transpose [B,C,S] f32 ->
// [B,S,C] bf16.  Block = 256 threads handles 64 s-columns x 256 channels.
// ---------------------------------------------------------------------------
__global__ __launch_bounds__(256) void norm_transpose_kernel(
    const float* __restrict__ src, const float* __restrict__ dst,
    __hip_bfloat16* __restrict__ srcT, __hip_bfloat16* __restrict__ dstT) {
    const int s0 = blockIdx.x * 64;
    const int b  = blockIdx.y;
    const float* in = (blockIdx.z == 0 ? src : dst) + (size_t)b * C_DIM * S_DIM;
    __hip_bfloat16* out = (blockIdx.z == 0 ? srcT : dstT) + (size_t)b * S_DIM * C_DIM;

    __shared__ __align__(16) __hip_bfloat16 tile[64][C_DIM + 8];
    __shared__ float red[4][64];
    __shared__ float invn[64];

    const int t  = threadIdx.x;
    const int l  = t & 63;
    const int wv = t >> 6;

    float ss = 0.f;
#pragma unroll 8
    for (int c = wv; c < C_DIM; c += 4) {
        float v = in[(size_t)c * S_DIM + s0 + l];
        ss += v * v;
        tile[l][c] = __float2bfloat16(v);
    }
    red[wv][l] = ss;
    __syncthreads();
    if (t < 64) invn[t] = rsqrtf(red[0][t] + red[1][t] + red[2][t] + red[3][t]);
    __syncthreads();

#pragma unroll
    for (int it = 0; it < 8; ++it) {
        int idx  = it * 256 + t;
        int srow = idx >> 5;
        int c0   = (idx & 31) << 3;
        float inv = invn[srow];
        union { short8 v; __hip_bfloat16 h[8]; } u, o;
        u.v = *(const short8*)&tile[srow][c0];
#pragma unroll
        for (int j = 0; j < 8; ++j)
            o.h[j] = __float2bfloat16(__bfloat162float(u.h[j]) * inv);
        *(short8*)&out[(size_t)(s0 + srow) * C_DIM + c0] = o.v;
    }
}

// ---------------------------------------------------------------------------
// Kernel 2: per-batch GEMM  out[b][m][n] = relu( sum_k At[b][m][k]*Bt[b][n][k] )
// Round-3 change: 1-D grid + XCD/batch-aware swizzle.  batch = id % 8 so all
// blocks of batch b land on XCD b (round-robin dispatch heuristic).  One
// batch's At+Bt = 2.36 MB fits a 4 MB XCD L2 -> the 18x tile re-reads become
// L2 hits instead of LLC traffic (~340 MB -> ~38 MB LLC fetch).
// ---------------------------------------------------------------------------
__global__ __launch_bounds__(256) void gemm_relu_kernel(
    const __hip_bfloat16* __restrict__ At, const __hip_bfloat16* __restrict__ Bt,
    float* __restrict__ out) {
    const int id = blockIdx.x;
    const int b  = id & 7;          // batch -> XCD (id%8 round-robin)
    const int q  = id >> 3;         // 0..323 tile index within batch
    const int m0 = (q % 18) * 128;
    const int n0 = (q / 18) * 128;
    const __hip_bfloat16* A  = At + (size_t)b * S_DIM * C_DIM;
    const __hip_bfloat16* Bp = Bt + (size_t)b * S_DIM * C_DIM;

    // LDS union: staging 2x(As+Bs) 128x32 bf16 (32 KB) / epilogue f32 [64][132].
    __shared__ __align__(16) unsigned char smem[33792];
    __hip_bfloat16* stg = (__hip_bfloat16*)smem;
    float* Cs = (float*)smem;

    const int t    = threadIdx.x;
    const int lane = t & 63;
    const int wv   = t >> 6;

    const int fm = lane & 15;          // m (or n) within 16x16 fragment
    const int kq = (lane >> 4) << 3;   // k offset 0/8/16/24
    const int wr = (wv >> 1) << 6;     // wave row origin (0 or 64)
    const int wc = (wv & 1) << 6;      // wave col origin (0 or 64)
    const int rq = (lane >> 4) << 2;   // C/D row quad

    // Staging: one 128x32 tile = 8 chunks of 1024 B (64 lanes x 16B).
    const int ch0   = wv * 2;
    const int e0    = ch0 * 512 + lane * 8;
    const int row0  = e0 >> 5;
    const int kc0   = e0 & 31;
    const int e1    = (ch0 + 1) * 512 + lane * 8;
    const int row1  = e1 >> 5;
    const int kc1   = e1 & 31;

    floatx4 acc[4][4] = {};

    // prologue: stage tile k0=0 into buffer 0
    gload_lds16(A  + (size_t)(m0 + row0) * C_DIM + kc0, stg + ch0 * 512);
    gload_lds16(A  + (size_t)(m0 + row1) * C_DIM + kc1, stg + (ch0 + 1) * 512);
    gload_lds16(Bp + (size_t)(n0 + row0) * C_DIM + kc0, stg + 8192 + ch0 * 512);
    gload_lds16(Bp + (size_t)(n0 + row1) * C_DIM + kc1, stg + 8192 + (ch0 + 1) * 512);

#pragma unroll
    for (int ki = 0; ki < 8; ++ki) {
        __syncthreads();

        if (ki < 7) {      // prefetch next tile into the other buffer
            int kn = (ki + 1) * 32;
            int pb = (ki + 1) & 1;
            gload_lds16(A  + (size_t)(m0 + row0) * C_DIM + (kn + kc0), stg + pb * 4096 + ch0 * 512);
            gload_lds16(A  + (size_t)(m0 + row1) * C_DIM + (kn + kc1), stg + pb * 4096 + (ch0 + 1) * 512);
            gload_lds16(Bp + (size_t)(n0 + row0) * C_DIM + (kn + kc0), stg + 8192 + pb * 4096 + ch0 * 512);
            gload_lds16(Bp + (size_t)(n0 + row1) * C_DIM + (kn + kc1), stg + 8192 + pb * 4096 + (ch0 + 1) * 512);
        }

        const __hip_bfloat16* AsP = stg + (ki & 1) * 4096;
        const __hip_bfloat16* BsP = stg + 8192 + (ki & 1) * 4096;
        short8 af[4], bf[4];
#pragma unroll
        for (int i = 0; i < 4; ++i) {
            af[i] = *(const short8*)&AsP[(wr + i * 16 + fm) * 32 + kq];
            bf[i] = *(const short8*)&BsP[(wc + i * 16 + fm) * 32 + kq];
        }
#pragma unroll
        for (int i = 0; i < 4; ++i)
#pragma unroll
            for (int j = 0; j < 4; ++j)
                acc[i][j] = __builtin_amdgcn_mfma_f32_16x16x32_bf16(af[i], bf[j], acc[i][j], 0, 0, 0);
    }

    // Epilogue: two rounds through Cs (64 rows x 132-padded f32), ReLU fused,
    // then coalesced float4 stores.
    float* Cp = out + (size_t)b * S_DIM * S_DIM;
#pragma unroll
    for (int p = 0; p < 2; ++p) {
        __syncthreads();
#pragma unroll
        for (int i2 = 0; i2 < 2; ++i2) {
            int i = 2 * p + i2;
            int slot = (wr >> 1) + i2 * 16 + rq;
#pragma unroll
            for (int j = 0; j < 4; ++j) {
                int col = wc + j * 16 + fm;
#pragma unroll
                for (int r = 0; r < 4; ++r)
                    Cs[(slot + r) * 132 + col] = fmaxf(acc[i][j][r], 0.f);
            }
        }
        __syncthreads();
#pragma unroll
        for (int it = 0; it < 8; ++it) {
            int idx  = it * 256 + t;
            int srow = idx >> 5;
            int c4   = (idx & 31) << 2;
            float4 v = *(const float4*)&Cs[srow * 132 + c4];
            int lrow = 32 * p + (srow & 31) + ((srow >> 5) << 6);
            *(float4*)&Cp[(size_t)(m0 + lrow) * S_DIM + n0 + c4] = v;
        }
    }
}

extern "C" void kernel_launch(void* const* d_in, const int* in_sizes, int n_in,
                              void* d_out, int out_size, void* d_ws, size_t ws_size,
                              hipStream_t stream) {
    const float* src = (const float*)d_in[0];
    const float* dst = (const float*)d_in[1];
    float* out = (float*)d_out;

    __hip_bfloat16* srcT = (__hip_bfloat16*)d_ws;
    __hip_bfloat16* dstT = srcT + (size_t)B_DIM * S_DIM * C_DIM;

    dim3 g1(S_DIM / 64, B_DIM, 2);
    norm_transpose_kernel<<<g1, 256, 0, stream>>>(src, dst, srcT, dstT);

    // 1-D swizzled grid: 8 batches x 18 x 18 tiles = 2592 blocks.
    gemm_relu_kernel<<<dim3(B_DIM * 18 * 18), 256, 0, stream>>>(srcT, dstT, out);
}

// Round 4
// 216.922 us; speedup vs baseline: 1.0226x; 1.0019x over previous
//
#include <hip/hip_runtime.h>
#include <hip/hip_bf16.h>

#define B_DIM 8
#define C_DIM 256
#define S_DIM 2304

typedef __attribute__((ext_vector_type(8))) short short8;
typedef __attribute__((ext_vector_type(4))) float floatx4;

// Barrier that drains ONLY LDS ops (lgkmcnt), leaving register-destined
// global loads in flight across the barrier. This is the whole point of the
// round-4 pipeline: __syncthreads() would force s_waitcnt vmcnt(0) and kill
// the prefetch overlap.
__device__ __forceinline__ void barrier_lgkm() {
    asm volatile("s_waitcnt lgkmcnt(0)\n\ts_barrier" ::: "memory");
}

// ---------------------------------------------------------------------------
// Kernel 1: per-(b,s) L2-normalize over C and transpose [B,C,S] f32 ->
// [B,S,C] bf16.  (unchanged; est. ~12 us)
// ---------------------------------------------------------------------------
__global__ __launch_bounds__(256) void norm_transpose_kernel(
    const float* __restrict__ src, const float* __restrict__ dst,
    __hip_bfloat16* __restrict__ srcT, __hip_bfloat16* __restrict__ dstT) {
    const int s0 = blockIdx.x * 64;
    const int b  = blockIdx.y;
    const float* in = (blockIdx.z == 0 ? src : dst) + (size_t)b * C_DIM * S_DIM;
    __hip_bfloat16* out = (blockIdx.z == 0 ? srcT : dstT) + (size_t)b * S_DIM * C_DIM;

    __shared__ __align__(16) __hip_bfloat16 tile[64][C_DIM + 8];
    __shared__ float red[4][64];
    __shared__ float invn[64];

    const int t  = threadIdx.x;
    const int l  = t & 63;
    const int wv = t >> 6;

    float ss = 0.f;
#pragma unroll 8
    for (int c = wv; c < C_DIM; c += 4) {
        float v = in[(size_t)c * S_DIM + s0 + l];
        ss += v * v;
        tile[l][c] = __float2bfloat16(v);
    }
    red[wv][l] = ss;
    __syncthreads();
    if (t < 64) invn[t] = rsqrtf(red[0][t] + red[1][t] + red[2][t] + red[3][t]);
    __syncthreads();

#pragma unroll
    for (int it = 0; it < 8; ++it) {
        int idx  = it * 256 + t;
        int srow = idx >> 5;
        int c0   = (idx & 31) << 3;
        float inv = invn[srow];
        union { short8 v; __hip_bfloat16 h[8]; } u, o;
        u.v = *(const short8*)&tile[srow][c0];
#pragma unroll
        for (int j = 0; j < 8; ++j)
            o.h[j] = __float2bfloat16(__bfloat162float(u.h[j]) * inv);
        *(short8*)&out[(size_t)(s0 + srow) * C_DIM + c0] = o.v;
    }
}

// ---------------------------------------------------------------------------
// Kernel 2: per-batch GEMM  out[b][m][n] = relu( sum_k At[b][m][k]*Bt[b][n][k] )
// Round-4: cp.async-style pipeline in HIP.
//   prologue: global_load tile 0 -> VGPRs
//   iter ki : ds_write regs -> buf[ki&1]   (vmcnt wait covers loads from ki-1,
//                                           hidden behind a full iteration)
//             global_load tile ki+1 -> regs (stays in flight ACROSS barrier)
//             s_waitcnt lgkmcnt(0); s_barrier   (no vmcnt drain!)
//             ds_read frags; 16x mfma_16x16x32_bf16
// WAR safety: buf[ki&1] was last read in iter ki-2, two barriers earlier.
// Keeps round-3 batch->XCD swizzle (batch = blockIdx.x % 8).
// ---------------------------------------------------------------------------
__global__ __launch_bounds__(256) void gemm_relu_kernel(
    const __hip_bfloat16* __restrict__ At, const __hip_bfloat16* __restrict__ Bt,
    float* __restrict__ out) {
    const int id = blockIdx.x;
    const int b  = id & 7;          // batch -> XCD (id%8 round-robin)
    const int q  = id >> 3;
    const int m0 = (q % 18) * 128;
    const int n0 = (q / 18) * 128;
    const __hip_bfloat16* A  = At + (size_t)b * S_DIM * C_DIM;
    const __hip_bfloat16* Bp = Bt + (size_t)b * S_DIM * C_DIM;

    // LDS: As[p] elems [p*4096, ...), Bs[p] elems [8192 + p*4096, ...)  (32 KB)
    // epilogue f32 Cs[64][132] aliased on top (33792 B).
    __shared__ __align__(16) unsigned char smem[33792];
    __hip_bfloat16* stg = (__hip_bfloat16*)smem;
    float* Cs = (float*)smem;

    const int t    = threadIdx.x;
    const int lane = t & 63;
    const int wv   = t >> 6;

    const int fm = lane & 15;
    const int kq = (lane >> 4) << 3;
    const int wr = (wv >> 1) << 6;
    const int wc = (wv & 1) << 6;
    const int rq = (lane >> 4) << 2;

    // Staging: tile = 8 chunks of 512 elems (64 lanes x 8 bf16); wave wv owns
    // chunks {2wv, 2wv+1}.  e = element offset within the 128x32 tile.
    const int e0   = wv * 1024 + lane * 8;
    const int row0 = e0 >> 5, kc0 = e0 & 31;
    const int e1   = e0 + 512;
    const int row1 = e1 >> 5, kc1 = e1 & 31;

    const __hip_bfloat16* gA0 = A  + (size_t)(m0 + row0) * C_DIM + kc0;
    const __hip_bfloat16* gA1 = A  + (size_t)(m0 + row1) * C_DIM + kc1;
    const __hip_bfloat16* gB0 = Bp + (size_t)(n0 + row0) * C_DIM + kc0;
    const __hip_bfloat16* gB1 = Bp + (size_t)(n0 + row1) * C_DIM + kc1;

    // prologue: tile 0 -> registers
    short8 rA0 = *(const short8*)gA0;
    short8 rA1 = *(const short8*)gA1;
    short8 rB0 = *(const short8*)gB0;
    short8 rB1 = *(const short8*)gB1;

    floatx4 acc[4][4] = {};

#pragma unroll
    for (int ki = 0; ki < 8; ++ki) {
        __hip_bfloat16* As = stg + (ki & 1) * 4096;
        __hip_bfloat16* Bs = stg + 8192 + (ki & 1) * 4096;

        // stage tile ki from regs into LDS (compiler inserts the vmcnt wait
        // for the loads issued one full iteration ago)
        *(short8*)(As + e0) = rA0;
        *(short8*)(As + e1) = rA1;
        *(short8*)(Bs + e0) = rB0;
        *(short8*)(Bs + e1) = rB1;

        // prefetch tile ki+1 -> regs; stays in flight across the barrier
        if (ki < 7) {
            int off = (ki + 1) * 32;
            rA0 = *(const short8*)(gA0 + off);
            rA1 = *(const short8*)(gA1 + off);
            rB0 = *(const short8*)(gB0 + off);
            rB1 = *(const short8*)(gB1 + off);
        }

        barrier_lgkm();   // drain LDS writes only; NO vmcnt drain

        short8 af[4], bf[4];
#pragma unroll
        for (int i = 0; i < 4; ++i) {
            af[i] = *(const short8*)&As[(wr + i * 16 + fm) * 32 + kq];
            bf[i] = *(const short8*)&Bs[(wc + i * 16 + fm) * 32 + kq];
        }
#pragma unroll
        for (int i = 0; i < 4; ++i)
#pragma unroll
            for (int j = 0; j < 4; ++j)
                acc[i][j] = __builtin_amdgcn_mfma_f32_16x16x32_bf16(af[i], bf[j], acc[i][j], 0, 0, 0);
    }

    // Epilogue: acc -> padded LDS f32 tile -> coalesced float4 stores, ReLU fused.
    float* Cp = out + (size_t)b * S_DIM * S_DIM;
#pragma unroll
    for (int p = 0; p < 2; ++p) {
        __syncthreads();   // all frag ds_reads / prior Cs reads done
#pragma unroll
        for (int i2 = 0; i2 < 2; ++i2) {
            int i = 2 * p + i2;
            int slot = (wr >> 1) + i2 * 16 + rq;
#pragma unroll
            for (int j = 0; j < 4; ++j) {
                int col = wc + j * 16 + fm;
#pragma unroll
                for (int r = 0; r < 4; ++r)
                    Cs[(slot + r) * 132 + col] = fmaxf(acc[i][j][r], 0.f);
            }
        }
        __syncthreads();
#pragma unroll
        for (int it = 0; it < 8; ++it) {
            int idx  = it * 256 + t;
            int srow = idx >> 5;
            int c4   = (idx & 31) << 2;
            float4 v = *(const float4*)&Cs[srow * 132 + c4];
            int lrow = 32 * p + (srow & 31) + ((srow >> 5) << 6);
            *(float4*)&Cp[(size_t)(m0 + lrow) * S_DIM + n0 + c4] = v;
        }
    }
}

extern "C" void kernel_launch(void* const* d_in, const int* in_sizes, int n_in,
                              void* d_out, int out_size, void* d_ws, size_t ws_size,
                              hipStream_t stream) {
    const float* src = (const float*)d_in[0];
    const float* dst = (const float*)d_in[1];
    float* out = (float*)d_out;

    __hip_bfloat16* srcT = (__hip_bfloat16*)d_ws;
    __hip_bfloat16* dstT = srcT + (size_t)B_DIM * S_DIM * C_DIM;

    dim3 g1(S_DIM / 64, B_DIM, 2);
    norm_transpose_kernel<<<g1, 256, 0, stream>>>(src, dst, srcT, dstT);

    gemm_relu_kernel<<<dim3(B_DIM * 18 * 18), 256, 0, stream>>>(srcT, dstT, out);
}